// Round 22
// baseline (288.501 us; speedup 1.0000x reference)
//
#include <hip/hip_runtime.h>

#define LOG2E 1.44269504088896340736f

typedef __attribute__((ext_vector_type(8))) _Float16 half8;
typedef __attribute__((ext_vector_type(2))) _Float16 h2;
typedef __attribute__((ext_vector_type(4))) float f32x4;

constexpr int CL       = 20;              // layers per staged chunk
constexpr int LAYER_BY = 2048;            // bytes/layer: 2 tiles x 64 lanes x 16B
constexpr int CHUNK_BY = CL * LAYER_BY;   // 40960
constexpr int CHUNK_V4 = CHUNK_BY / 16;   // 2560 float4
constexpr int V4_PER_T = CHUNK_V4 / 256;  // 10 per thread

// k-slot -> logical input position (same map in prepack/A and runtime/B, so
// the HW k-order cancels; layout family proven by bf16-K32 absmax 0.0).
// pos 20 carries bias (B supplies 1.0); pos>20 pad=0.
__device__ __forceinline__ int slot_pos(int h, int e) {
    return (e < 4) ? (4 * h + e) : (16 + 4 * h + (e - 4));
}

__device__ __forceinline__ unsigned short f16_rne(float f) {
    _Float16 h = (_Float16)f;   // RNE
    return __builtin_bit_cast(unsigned short, h);
}

// One block per layer; 128 threads = 2 tiles x 64 lanes. Weights/bias are
// PRE-SCALED by 0.5: acc = 0.5*z = x, feeding the Pade sigmoid directly.
__global__ void prepack(const float* __restrict__ W, const float* __restrict__ b,
                        unsigned int* __restrict__ wstream, int L)
{
    const int l    = blockIdx.x;
    const int t    = threadIdx.x >> 6;
    const int lane = threadIdx.x & 63;
    const int n    = t * 16 + (lane & 15);   // output-neuron position
    const int h    = lane >> 4;
    unsigned int words[4];
#pragma unroll
    for (int d = 0; d < 4; ++d) {
        unsigned short halves[2];
#pragma unroll
        for (int half = 0; half < 2; ++half) {
            int e   = d * 2 + half;
            int pos = slot_pos(h, e);
            float v = 0.f;
            if (n < 20) {
                if (pos < 20)       v = W[(size_t)l * 400 + n * 20 + pos];
                else if (pos == 20) v = b[(size_t)l * 20 + n];
            }
            halves[half] = f16_rne(v * 0.5f);
        }
        words[d] = (unsigned)halves[0] | ((unsigned)halves[1] << 16);
    }
    unsigned int* dst = wstream + ((size_t)l * LAYER_BY + t * 1024 + lane * 16) / 4;
    dst[0] = words[0]; dst[1] = words[1]; dst[2] = words[2]; dst[3] = words[3];
}

__device__ __forceinline__ unsigned pkrtz(float a, float b) {
    auto r = __builtin_amdgcn_cvt_pkrtz(a, b);   // __fp16 ext_vector(2)
    return __builtin_bit_cast(unsigned, r);
}

__device__ __forceinline__ h2 mkh2(unsigned u) { return __builtin_bit_cast(h2, u); }

// sigmoid(z) with x = 0.5*z (scale folded into weights), PACKED f16:
// sigma = 0.5 + x*N(u)/D(u), u = x^2; N = 0.5u^2+52.5u+472.5,
// D = 15u^2+420u+945. All poly ops are v_pk_*_f16 (2 values/issue); two
// scalar v_rcp_f16 per word. Output word IS the next B-fragment word.
// f16 range check: u<=17.6, N<=1551, D<=12983 < 65504. Injected err
// ~1.5e-3/layer, contraction 0.5 -> steady ~5e-3 activation, ~1e-3 output.
__device__ __forceinline__ unsigned pade_sig_pk(float a, float b,
        h2 c05, h2 c525, h2 c4725, h2 c15, h2 c420, h2 c945) {
    h2 w = mkh2(pkrtz(a, b));        // x pair in f16
    h2 u = w * w;
    h2 t = u * c05 + c525;
    h2 n = t * u + c4725;
    h2 s = u * c15 + c420;
    h2 d = s * u + c945;
    unsigned du = __builtin_bit_cast(unsigned, d);
    unsigned dh = du >> 16;
    unsigned il, ih;
    asm("v_rcp_f16 %0, %1" : "=v"(il) : "v"(du));   // rcp(d.lo) in [15:0]
    asm("v_rcp_f16 %0, %1" : "=v"(ih) : "v"(dh));   // rcp(d.hi) in [15:0]
    unsigned iv = (ih << 16) | (il & 0xffffu);
    h2 m = w * n;
    h2 r = m * mkh2(iv) + c05;
    return __builtin_bit_cast(unsigned, r);
}

// full sigmoid for unscaled z (epilogue only, once)
__device__ __forceinline__ float sigm(float z) {
    return __builtin_amdgcn_rcpf(1.f + __builtin_amdgcn_exp2f(-LOG2E * z));
}

// Issue both A-fragment reads for one layer (volatile -> cannot be sunk).
__device__ __forceinline__ void issue_frag(unsigned addr, half8& t0, half8& t1) {
    asm volatile("ds_read_b128 %0, %1 offset:0"    : "=v"(t0) : "v"(addr));
    asm volatile("ds_read_b128 %0, %1 offset:1024" : "=v"(t1) : "v"(addr));
}

__device__ __forceinline__ void layer_step(const half8& c0, const half8& c1,
                                           half8& Bf, unsigned (&qw)[4], int h,
                                           h2 k05, h2 k525, h2 k4725,
                                           h2 k15, h2 k420, h2 k945) {
    const f32x4 zero = {0.f, 0.f, 0.f, 0.f};
    f32x4 acc0 = __builtin_amdgcn_mfma_f32_16x16x32_f16(c0, Bf, zero, 0, 0, 0);
    f32x4 acc1 = __builtin_amdgcn_mfma_f32_16x16x32_f16(c1, Bf, zero, 0, 0, 0);
    unsigned p0 = pade_sig_pk(acc0[0], acc0[1], k05, k525, k4725, k15, k420, k945);
    unsigned p1 = pade_sig_pk(acc0[2], acc0[3], k05, k525, k4725, k15, k420, k945);
    unsigned p2 = pade_sig_pk(acc1[0], acc1[1], k05, k525, k4725, k15, k420, k945);
    unsigned p3 = pade_sig_pk(acc1[2], acc1[3], k05, k525, k4725, k15, k420, k945);
    qw[0] = p0; qw[1] = p1; qw[2] = p2; qw[3] = p3;
    // Mask pad slots: h==0 keeps pos 16..19; h==1 e4 = bias multiplier 1.0.
    unsigned w2 = (h == 0) ? p2 : ((h == 1) ? 0x00003C00u : 0u);
    unsigned w3 = (h == 0) ? p3 : 0u;
    union { unsigned u[4]; half8 v; } cv;
    cv.u[0] = p0; cv.u[1] = p1; cv.u[2] = w2; cv.u[3] = w3;
    Bf = cv.v;
}

// 16 batch rows per wave via 16x16x32 f16 MFMA; 1024 waves = 1/SIMD
// (structural). r9-proven LDS skeleton: dist-2 ds_read pipeline, counted
// lgkmcnt(2); packed-f16 sigmoid whose output words ARE the B fragment.
__global__ __launch_bounds__(256, 1) void mann_mfma(
    const float* __restrict__ x, const unsigned int* __restrict__ wstream,
    const float* __restrict__ Wout, const float* __restrict__ bout,
    float* __restrict__ out, int B, int L)
{
    __shared__ unsigned char lds[2 * CHUNK_BY];   // 80 KiB double buffer

    const int tid  = threadIdx.x;
    const int lane = tid & 63;
    const int c16  = lane & 15;     // batch column within wave
    const int h    = lane >> 4;     // k-group / D-row group
    const int w    = (blockIdx.x * 256 + tid) >> 6;  // global wave id
    const int row  = w * 16 + c16;  // this lane's batch row

    // Packed-f16 Pade constants (pairs of identical halves).
    const h2 k05   = mkh2(0x38003800u);   // 0.5
    const h2 k525  = mkh2(0x52905290u);   // 52.5
    const h2 k4725 = mkh2(0x5F625F62u);   // 472.5
    const h2 k15   = mkh2(0x4B804B80u);   // 15.0
    const h2 k420  = mkh2(0x5E905E90u);   // 420.0
    const h2 k945  = mkh2(0x63626362u);   // 945.0

    // ---- first-layer B fragment from x (unscaled; 0.5 lives in A) ----
    const float4 xa = *reinterpret_cast<const float4*>(x + (size_t)row * 20 + 4 * h);
    const float4 xb = *reinterpret_cast<const float4*>(x + (size_t)row * 20 + 16);
    {
        unsigned iw2 = (h == 0) ? pkrtz(xb.x, xb.y) : ((h == 1) ? 0x00003C00u : 0u);
        unsigned iw3 = (h == 0) ? pkrtz(xb.z, xb.w) : 0u;
        union { unsigned u[4]; half8 v; } cv;
        cv.u[0] = pkrtz(xa.x, xa.y); cv.u[1] = pkrtz(xa.z, xa.w);
        cv.u[2] = iw2; cv.u[3] = iw3;
        // Bf initialized below via this union
        __builtin_memcpy(nullptr, nullptr, 0);  // no-op
    }
    union { unsigned u[4]; half8 v; } bf0;
    bf0.u[0] = pkrtz(xa.x, xa.y);
    bf0.u[1] = pkrtz(xa.z, xa.w);
    bf0.u[2] = (h == 0) ? pkrtz(xb.x, xb.y) : ((h == 1) ? 0x00003C00u : 0u);
    bf0.u[3] = (h == 0) ? pkrtz(xb.z, xb.w) : 0u;
    half8 Bf = bf0.v;

    // ---- chunk staging: global->reg early, reg->LDS late ----
    float4 sreg[V4_PER_T];
    auto stage_load = [&](int c) {
        const float4* g = reinterpret_cast<const float4*>(wstream) + (size_t)c * CHUNK_V4;
#pragma unroll
        for (int j = 0; j < V4_PER_T; ++j) sreg[j] = g[j * 256 + tid];
    };
    auto stage_write = [&](int bufi) {
        float4* d = reinterpret_cast<float4*>(lds + bufi * CHUNK_BY);
#pragma unroll
        for (int j = 0; j < V4_PER_T; ++j) d[j * 256 + tid] = sreg[j];
    };

    const unsigned lbase = (unsigned)(uintptr_t)&lds[0];

    stage_load(0); stage_write(0); __syncthreads();

    // 4 named A-fragment buffers; buf[l & 3] holds layer l's fragments.
    half8 f0a, f0b, f1a, f1b, f2a, f2b, f3a, f3b;

    const unsigned cb0 = lbase + lane * 16;
    issue_frag(cb0,            f0a, f0b);   // layer 0
    issue_frag(cb0 + LAYER_BY, f1a, f1b);   // layer 1

    unsigned qw[4];

    const int NC = L / CL;   // 50
    for (int c = 0; c < NC; ++c) {
        if (c + 1 < NC) stage_load(c + 1);           // global prefetch (vmcnt)
        const unsigned cb = lbase + (c & 1) * CHUNK_BY + lane * 16;
#pragma unroll
        for (int ll = 0; ll < CL; ++ll) {
            // Counted wait: 4 reads outstanding (ll, ll+1); wait oldest 2.
            if (ll == CL - 1) asm volatile("s_waitcnt lgkmcnt(0)");
            else              asm volatile("s_waitcnt lgkmcnt(2)");
            __builtin_amdgcn_sched_barrier(0);       // rule #18
            if (ll + 2 < CL) {
                const unsigned a = cb + (ll + 2) * LAYER_BY;
                const int bi = (ll + 2) & 3;
                if      (bi == 0) issue_frag(a, f0a, f0b);
                else if (bi == 1) issue_frag(a, f1a, f1b);
                else if (bi == 2) issue_frag(a, f2a, f2b);
                else              issue_frag(a, f3a, f3b);
            }
            __builtin_amdgcn_sched_barrier(0);
            const int ci = ll & 3;
            if      (ci == 0) layer_step(f0a, f0b, Bf, qw, h, k05, k525, k4725, k15, k420, k945);
            else if (ci == 1) layer_step(f1a, f1b, Bf, qw, h, k05, k525, k4725, k15, k420, k945);
            else if (ci == 2) layer_step(f2a, f2b, Bf, qw, h, k05, k525, k4725, k15, k420, k945);
            else              layer_step(f3a, f3b, Bf, qw, h, k05, k525, k4725, k15, k420, k945);
        }
        if (c + 1 < NC) {
            stage_write((c + 1) & 1);                // loads long since landed
            __syncthreads();
            const unsigned nb = lbase + ((c + 1) & 1) * CHUNK_BY + lane * 16;
            issue_frag(nb,            f0a, f0b);     // next chunk layer 0
            issue_frag(nb + LAYER_BY, f1a, f1b);     // next chunk layer 1
        }
    }

    // ---- epilogue: lane (h,c16) holds neurons {4h+j} (qw[0],qw[1]) and
    // {16+4h+j} (qw[2],qw[3]; real only for h==0) ----
    h2 r0 = mkh2(qw[0]), r1 = mkh2(qw[1]), r2 = mkh2(qw[2]), r3 = mkh2(qw[3]);
    const float4 woa = *reinterpret_cast<const float4*>(Wout + 4 * h);
    const float4 wob = *reinterpret_cast<const float4*>(Wout + 16);
    float part = (float)r0.x * woa.x + (float)r0.y * woa.y
               + (float)r1.x * woa.z + (float)r1.y * woa.w;
    const float m = (h == 0) ? 1.f : 0.f;
    part += m * ((float)r2.x * wob.x + (float)r2.y * wob.y
               + (float)r3.x * wob.z + (float)r3.y * wob.w);
    part += __shfl_xor(part, 16, 64);
    part += __shfl_xor(part, 32, 64);
    if (h == 0) out[row] = sigm(part + bout[0]);
}

extern "C" void kernel_launch(void* const* d_in, const int* in_sizes, int n_in,
                              void* d_out, int out_size, void* d_ws, size_t ws_size,
                              hipStream_t stream) {
    const float* x    = (const float*)d_in[0];
    const float* W    = (const float*)d_in[1];
    const float* b    = (const float*)d_in[2];
    const float* Wout = (const float*)d_in[3];
    const float* bout = (const float*)d_in[4];
    float* out = (float*)d_out;

    const int B = in_sizes[0] / 20;    // 16384
    const int L = in_sizes[1] / 400;   // 1000

    unsigned int* wstream = (unsigned int*)d_ws;   // L*2048 B = 2.05 MB

    prepack<<<L, 128, 0, stream>>>(W, b, wstream, L);

    const int grid = B / 64;           // 16 rows/wave, 4 waves/block
    mann_mfma<<<grid, 256, 0, stream>>>(x, wstream, Wout, bout, out, B, L);
}

// Round 23
// 271.615 us; speedup vs baseline: 1.0622x; 1.0622x over previous
//
#include <hip/hip_runtime.h>

#define LOG2E 1.44269504088896340736f

typedef __attribute__((ext_vector_type(8))) short short8;
typedef __attribute__((ext_vector_type(4))) float f32x4;
typedef __attribute__((ext_vector_type(2))) float f32x2;

constexpr int CL       = 20;              // layers per staged chunk
constexpr int LAYER_BY = 2048;            // bytes/layer: 2 tiles x 64 lanes x 16B
constexpr int CHUNK_BY = CL * LAYER_BY;   // 40960
constexpr int CHUNK_V4 = CHUNK_BY / 16;   // 2560 float4
constexpr int V4_PER_T = CHUNK_V4 / 256;  // 10 per thread

// k-slot -> logical input position (same map in prepack/A and runtime/B, so
// the HW k-order cancels). pos 20 carries bias (B supplies 1.0); pos>20 pad=0.
__device__ __forceinline__ int slot_pos(int h, int e) {
    return (e < 4) ? (4 * h + e) : (16 + 4 * h + (e - 4));
}

__device__ __forceinline__ unsigned short f32_to_bf16_rne(float f) {
    unsigned u = __builtin_bit_cast(unsigned, f);
    unsigned r = 0x7fffu + ((u >> 16) & 1u);
    return (unsigned short)((u + r) >> 16);
}

// One block per layer; 128 threads = 2 tiles x 64 lanes. Weights/bias are
// PRE-SCALED by 0.5: acc = 0.5*z = x, feeding the Pade sigmoid directly.
__global__ void prepack(const float* __restrict__ W, const float* __restrict__ b,
                        unsigned int* __restrict__ wstream, int L)
{
    const int l    = blockIdx.x;
    const int t    = threadIdx.x >> 6;
    const int lane = threadIdx.x & 63;
    const int n    = t * 16 + (lane & 15);   // output-neuron position
    const int h    = lane >> 4;
    unsigned int words[4];
#pragma unroll
    for (int d = 0; d < 4; ++d) {
        unsigned short halves[2];
#pragma unroll
        for (int half = 0; half < 2; ++half) {
            int e   = d * 2 + half;
            int pos = slot_pos(h, e);
            float v = 0.f;
            if (n < 20) {
                if (pos < 20)       v = W[(size_t)l * 400 + n * 20 + pos];
                else if (pos == 20) v = b[(size_t)l * 20 + n];
            }
            halves[half] = f32_to_bf16_rne(v * 0.5f);
        }
        words[d] = (unsigned)halves[0] | ((unsigned)halves[1] << 16);
    }
    unsigned int* dst = wstream + ((size_t)l * LAYER_BY + t * 1024 + lane * 16) / 4;
    dst[0] = words[0]; dst[1] = words[1]; dst[2] = words[2]; dst[3] = words[3];
}

__device__ __forceinline__ unsigned cvt_pk_bf16(float lo, float hi) {
    unsigned r;
    asm("v_cvt_pk_bf16_f32 %0, %1, %2" : "=v"(r) : "v"(lo), "v"(hi));
    return r;
}

// Mask pad slots: h==0 keeps real positions 16..19; h==1 slot e=4 is pos 20
// -> constant 1.0 (bias multiplier); other upper-half slots hit zero A columns.
__device__ __forceinline__ short8 finalize_B(unsigned p0, unsigned p1,
                                             unsigned p2, unsigned p3, int h) {
    if (h != 0) { p2 = (h == 1) ? 0x00003F80u : 0u; p3 = 0u; }
    union { unsigned u[4]; short8 s; } cv;
    cv.u[0] = p0; cv.u[1] = p1; cv.u[2] = p2; cv.u[3] = p3;
    return cv.s;
}

__device__ __forceinline__ f32x2 make2(float v) { f32x2 r; r.x = v; r.y = v; return r; }

// sigmoid(z) with x = 0.5*z already in acc: sigma = 0.5 + x*Ntil(u)/D(u),
// u = x^2. abs err <= ~2e-5 for |z|<=4, <= 1.2e-3 at |z|=8.
__device__ __forceinline__ f32x2 pade_sig(f32x2 x) {
    f32x2 u = x * x;
    f32x2 n = (u * make2(0.5f) + make2(52.5f)) * u + make2(472.5f);
    f32x2 d = (u * make2(15.0f) + make2(420.0f)) * u + make2(945.0f);
    f32x2 r;
    r.x = __builtin_amdgcn_rcpf(d.x);
    r.y = __builtin_amdgcn_rcpf(d.y);
    return (x * n) * r + make2(0.5f);
}

// full sigmoid for unscaled z (epilogue only, once)
__device__ __forceinline__ float sigm(float z) {
    return __builtin_amdgcn_rcpf(1.f + __builtin_amdgcn_exp2f(-LOG2E * z));
}

// Issue both A-fragment reads for one layer (volatile -> cannot be sunk).
__device__ __forceinline__ void issue_frag(unsigned addr, short8& t0, short8& t1) {
    asm volatile("ds_read_b128 %0, %1 offset:0"    : "=v"(t0) : "v"(addr));
    asm volatile("ds_read_b128 %0, %1 offset:1024" : "=v"(t1) : "v"(addr));
}

__device__ __forceinline__ void layer_step(const short8& c0, const short8& c1,
                                           short8& Bf, f32x2& q0, f32x2& q1,
                                           f32x2& q2, f32x2& q3, int h) {
    const f32x4 zero = {0.f, 0.f, 0.f, 0.f};
    f32x4 acc0 = __builtin_amdgcn_mfma_f32_16x16x32_bf16(c0, Bf, zero, 0, 0, 0);
    f32x4 acc1 = __builtin_amdgcn_mfma_f32_16x16x32_bf16(c1, Bf, zero, 0, 0, 0);
    q0.x = acc0[0]; q0.y = acc0[1];
    q1.x = acc0[2]; q1.y = acc0[3];
    q2.x = acc1[0]; q2.y = acc1[1];
    q3.x = acc1[2]; q3.y = acc1[3];
    q0 = pade_sig(q0); q1 = pade_sig(q1);
    q2 = pade_sig(q2); q3 = pade_sig(q3);
    Bf = finalize_B(cvt_pk_bf16(q0.x, q0.y), cvt_pk_bf16(q1.x, q1.y),
                    cvt_pk_bf16(q2.x, q2.y), cvt_pk_bf16(q3.x, q3.y), h);
}

// 16 batch rows per wave via 16x16x32 MFMA; 1024 waves = 1/SIMD (structural).
// A-fragments prefetched 2 LAYERS ahead (4 named buffers, counted lgkmcnt(2)
// waits) so the ds_read latency is fully covered by ~2 layers of compute.
__global__ __launch_bounds__(256, 1) void mann_mfma(
    const float* __restrict__ x, const unsigned int* __restrict__ wstream,
    const float* __restrict__ Wout, const float* __restrict__ bout,
    float* __restrict__ out, int B, int L)
{
    __shared__ unsigned char lds[2 * CHUNK_BY];   // 80 KiB double buffer

    const int tid  = threadIdx.x;
    const int lane = tid & 63;
    const int c16  = lane & 15;     // batch column within wave
    const int h    = lane >> 4;     // k-group / D-row group
    const int w    = (blockIdx.x * 256 + tid) >> 6;  // global wave id
    const int row  = w * 16 + c16;  // this lane's batch row

    // ---- first-layer B fragment from x ----
    const float4 xa = *reinterpret_cast<const float4*>(x + (size_t)row * 20 + 4 * h);
    const float4 xb = *reinterpret_cast<const float4*>(x + (size_t)row * 20 + 16);
    short8 Bf = finalize_B(cvt_pk_bf16(xa.x, xa.y), cvt_pk_bf16(xa.z, xa.w),
                           cvt_pk_bf16(xb.x, xb.y), cvt_pk_bf16(xb.z, xb.w), h);

    // ---- chunk staging: global->reg early, reg->LDS late ----
    float4 sreg[V4_PER_T];
    auto stage_load = [&](int c) {
        const float4* g = reinterpret_cast<const float4*>(wstream) + (size_t)c * CHUNK_V4;
#pragma unroll
        for (int j = 0; j < V4_PER_T; ++j) sreg[j] = g[j * 256 + tid];
    };
    auto stage_write = [&](int bufi) {
        float4* d = reinterpret_cast<float4*>(lds + bufi * CHUNK_BY);
#pragma unroll
        for (int j = 0; j < V4_PER_T; ++j) d[j * 256 + tid] = sreg[j];
    };

    const unsigned lbase = (unsigned)(uintptr_t)&lds[0];

    stage_load(0); stage_write(0); __syncthreads();

    // 4 named A-fragment buffers; buf[l & 3] holds layer l's fragments.
    short8 f0a, f0b, f1a, f1b, f2a, f2b, f3a, f3b;

    const unsigned cb0 = lbase + lane * 16;
    issue_frag(cb0,            f0a, f0b);   // layer 0
    issue_frag(cb0 + LAYER_BY, f1a, f1b);   // layer 1

    f32x2 q0, q1, q2, q3;

    const int NC = L / CL;   // 50
    for (int c = 0; c < NC; ++c) {
        if (c + 1 < NC) stage_load(c + 1);           // global prefetch (vmcnt)
        const unsigned cb = lbase + (c & 1) * CHUNK_BY + lane * 16;
#pragma unroll
        for (int ll = 0; ll < CL; ++ll) {
            // Counted wait: 4 reads outstanding (ll, ll+1); wait oldest 2.
            if (ll == CL - 1) asm volatile("s_waitcnt lgkmcnt(0)");
            else              asm volatile("s_waitcnt lgkmcnt(2)");
            __builtin_amdgcn_sched_barrier(0);       // rule #18
            if (ll + 2 < CL) {
                const unsigned a = cb + (ll + 2) * LAYER_BY;
                const int bi = (ll + 2) & 3;
                if      (bi == 0) issue_frag(a, f0a, f0b);
                else if (bi == 1) issue_frag(a, f1a, f1b);
                else if (bi == 2) issue_frag(a, f2a, f2b);
                else              issue_frag(a, f3a, f3b);
            }
            __builtin_amdgcn_sched_barrier(0);
            const int ci = ll & 3;
            if      (ci == 0) layer_step(f0a, f0b, Bf, q0, q1, q2, q3, h);
            else if (ci == 1) layer_step(f1a, f1b, Bf, q0, q1, q2, q3, h);
            else if (ci == 2) layer_step(f2a, f2b, Bf, q0, q1, q2, q3, h);
            else              layer_step(f3a, f3b, Bf, q0, q1, q2, q3, h);
        }
        if (c + 1 < NC) {
            stage_write((c + 1) & 1);                // loads long since landed
            __syncthreads();
            const unsigned nb = lbase + ((c + 1) & 1) * CHUNK_BY + lane * 16;
            issue_frag(nb,            f0a, f0b);     // next chunk layer 0
            issue_frag(nb + LAYER_BY, f1a, f1b);     // next chunk layer 1
        }
    }

    // ---- epilogue: lane (h,c16) holds neurons {4h+j} (q0,q1) and
    // {16+4h+j} (q2,q3; real only for h==0) ----
    const float4 woa = *reinterpret_cast<const float4*>(Wout + 4 * h);
    const float4 wob = *reinterpret_cast<const float4*>(Wout + 16);
    float part = q0.x * woa.x + q0.y * woa.y + q1.x * woa.z + q1.y * woa.w;
    const float m = (h == 0) ? 1.f : 0.f;
    part += m * (q2.x * wob.x + q2.y * wob.y + q3.x * wob.z + q3.y * wob.w);
    part += __shfl_xor(part, 16, 64);
    part += __shfl_xor(part, 32, 64);
    if (h == 0) out[row] = sigm(part + bout[0]);
}

extern "C" void kernel_launch(void* const* d_in, const int* in_sizes, int n_in,
                              void* d_out, int out_size, void* d_ws, size_t ws_size,
                              hipStream_t stream) {
    const float* x    = (const float*)d_in[0];
    const float* W    = (const float*)d_in[1];
    const float* b    = (const float*)d_in[2];
    const float* Wout = (const float*)d_in[3];
    const float* bout = (const float*)d_in[4];
    float* out = (float*)d_out;

    const int B = in_sizes[0] / 20;    // 16384
    const int L = in_sizes[1] / 400;   // 1000

    unsigned int* wstream = (unsigned int*)d_ws;   // L*2048 B = 2.05 MB

    prepack<<<L, 128, 0, stream>>>(W, b, wstream, L);

    const int grid = B / 64;           // 16 rows/wave, 4 waves/block
    mann_mfma<<<grid, 256, 0, stream>>>(x, wstream, Wout, bout, out, B, L);
}